// Round 3
// baseline (154.276 us; speedup 1.0000x reference)
//
#include <hip/hip_runtime.h>

// RSNA loss: pred/label [128, 8192, 10] fp32, seq_lens [128] i32 -> scalar fp32.
//
// Single fused kernel (threadfence-reduction pattern):
//   grid (128 rows x SPLIT), 256 thr. Each block sums its chunk of the masked
//   prefix (2 records = 80 B = 5x float4 per thread per step), atomicAdds 20
//   partials into row_acc[b]. Last block per row (ticket) re-reads the row
//   sums (atomicAdd+0 for device-scope coherence), applies the nonlinear
//   exam-BCE / image weighting, atomicAdds (numer, wext) to global pair.
//   Last row's finalizer (2nd ticket) writes out[0].
//   A small memset node zeroes row_acc + accumulators + tickets (10.8 KB).
//
// Only l < seq_lens[b] is ever read -> ~half of the 84 MB input traffic.

#define L_DIM 8192
#define B_DIM 128
#define C_DIM 10
#define SPLIT 8

#define IMAGE_WEIGHT 0.0736196319f

// d_ws float-index layout
#define GNUM_IDX 2560       // after row_acc[128][20]
#define GWEXT_IDX 2561
#define ICTR_IDX 2562       // int row_done[128] + int rows_done, overlaid
#define WS_ZERO_BYTES ((2562 + 129) * 4)  // 10764 B

__device__ __constant__ float EXAM_W[9] = {
    0.0736196319f, 0.09202453988f, 0.1042944785f, 0.1042944785f,
    0.1877300613f, 0.06257668712f, 0.06257668712f, 0.2346625767f,
    0.0782208589f};

__device__ __forceinline__ float bce0(float p, float y) {
  return -(y * __logf(p) + (1.0f - y) * __logf(1.0f - p));
}

__global__ __launch_bounds__(256) void rsna_fused_kernel(
    const float* __restrict__ pred, const float* __restrict__ label,
    const int* __restrict__ seq_lens, float* __restrict__ ws,
    float* __restrict__ out) {
  const int b = blockIdx.x;  // 0..127
  const int s = blockIdx.y;  // 0..SPLIT-1
  const int len = seq_lens[b];
  // Even chunk so every block's start record is even (80 B pair, 16B-aligned).
  const int chunk = ((len + 2 * SPLIT - 1) / (2 * SPLIT)) * 2;
  const int start = s * chunk;
  const int end = min(start + chunk, len);

  float sp[9], sl[9];
#pragma unroll
  for (int c = 0; c < 9; ++c) {
    sp[c] = 0.0f;
    sl[c] = 0.0f;
  }
  float sy0 = 0.0f;
  float sbce = 0.0f;

  for (int l = start + 2 * (int)threadIdx.x; l < end; l += 512) {
    const size_t base = ((size_t)b * L_DIM + (size_t)l) * C_DIM;
    if (l + 1 < end) {
      const float4* p4 = reinterpret_cast<const float4*>(pred + base);
      const float4* y4 = reinterpret_cast<const float4*>(label + base);
      float p[20], y[20];
#pragma unroll
      for (int i = 0; i < 5; ++i) {
        float4 pv = p4[i];
        float4 yv = y4[i];
        p[4 * i] = pv.x; p[4 * i + 1] = pv.y; p[4 * i + 2] = pv.z; p[4 * i + 3] = pv.w;
        y[4 * i] = yv.x; y[4 * i + 1] = yv.y; y[4 * i + 2] = yv.z; y[4 * i + 3] = yv.w;
      }
#pragma unroll
      for (int c = 0; c < 9; ++c) {
        sp[c] += p[c + 1] + p[c + 11];
        sl[c] += y[c + 1] + y[c + 11];
      }
      sy0 += y[0] + y[10];
      sbce += bce0(p[0], y[0]) + bce0(p[10], y[10]);
    } else {
      const float2* p2 = reinterpret_cast<const float2*>(pred + base);
      const float2* y2 = reinterpret_cast<const float2*>(label + base);
      float p[10], y[10];
#pragma unroll
      for (int i = 0; i < 5; ++i) {
        float2 pv = p2[i];
        float2 yv = y2[i];
        p[2 * i] = pv.x; p[2 * i + 1] = pv.y;
        y[2 * i] = yv.x; y[2 * i + 1] = yv.y;
      }
#pragma unroll
      for (int c = 0; c < 9; ++c) {
        sp[c] += p[c + 1];
        sl[c] += y[c + 1];
      }
      sy0 += y[0];
      sbce += bce0(p[0], y[0]);
    }
  }

  // Block reduction of the 20 partials.
  float vals[20];
#pragma unroll
  for (int c = 0; c < 9; ++c) {
    vals[c] = sp[c];
    vals[9 + c] = sl[c];
  }
  vals[18] = sy0;
  vals[19] = sbce;

#pragma unroll
  for (int i = 0; i < 20; ++i) {
    float v = vals[i];
#pragma unroll
    for (int off = 32; off > 0; off >>= 1) v += __shfl_down(v, off, 64);
    vals[i] = v;
  }

  __shared__ float lds[4][20];
  const int wave = threadIdx.x >> 6;
  const int lane = threadIdx.x & 63;
  if (lane == 0) {
#pragma unroll
    for (int i = 0; i < 20; ++i) lds[wave][i] = vals[i];
  }
  __syncthreads();
  if (threadIdx.x < 20) {
    const float v = lds[0][threadIdx.x] + lds[1][threadIdx.x] +
                    lds[2][threadIdx.x] + lds[3][threadIdx.x];
    atomicAdd(&ws[b * 20 + (int)threadIdx.x], v);
  }
  // Barrier drains each wave's vmem ops -> all 20 row atomics complete.
  __syncthreads();

  int* ictr = (int*)(ws + ICTR_IDX);  // [0..127]=row tickets, [128]=row count

  if (threadIdx.x < 64) {  // wave 0 only from here on
    int t = 0;
    if (threadIdx.x == 0) {
      __threadfence();
      t = atomicAdd(&ictr[b], 1);
    }
    t = __shfl(t, 0, 64);
    if (t == SPLIT - 1) {
      // Last block for row b: re-read row sums coherently, finalize the row.
      float v = 0.0f;
      if (threadIdx.x < 20) v = atomicAdd(&ws[b * 20 + (int)threadIdx.x], 0.0f);
      float r[20];
#pragma unroll
      for (int i = 0; i < 20; ++i) r[i] = __shfl(v, i, 64);
      if (threadIdx.x == 0) {
        const float inv_len = 1.0f / (float)len;
        float exam = 0.0f;
#pragma unroll
        for (int c = 0; c < 9; ++c) {
          const float pm = r[c] * inv_len;
          const float ym = r[9 + c] * inv_len;
          exam += EXAM_W[c] *
                  (-(ym * __logf(pm) + (1.0f - ym) * __logf(1.0f - pm)));
        }
        const float img_w = IMAGE_WEIGHT * r[18] * inv_len;
        const float numer = exam + r[19] * img_w;  // row loss
        const float wext = IMAGE_WEIGHT * r[18];   // img_w * len
        atomicAdd(&ws[GNUM_IDX], numer);
        atomicAdd(&ws[GWEXT_IDX], wext);
        __threadfence();
        const int t2 = atomicAdd(&ictr[B_DIM], 1);
        if (t2 == B_DIM - 1) {
          const float n = atomicAdd(&ws[GNUM_IDX], 0.0f);
          const float w = atomicAdd(&ws[GWEXT_IDX], 0.0f);
          float wsum = 0.0f;
#pragma unroll
          for (int c = 0; c < 9; ++c) wsum += EXAM_W[c];
          out[0] = n / ((float)B_DIM * wsum + w);
        }
      }
    }
  }
}

extern "C" void kernel_launch(void* const* d_in, const int* in_sizes, int n_in,
                              void* d_out, int out_size, void* d_ws,
                              size_t ws_size, hipStream_t stream) {
  const float* pred = (const float*)d_in[0];
  const float* label = (const float*)d_in[1];
  const int* seq_lens = (const int*)d_in[2];
  float* ws = (float*)d_ws;

  hipMemsetAsync(d_ws, 0, WS_ZERO_BYTES, stream);
  dim3 grid(B_DIM, SPLIT);
  rsna_fused_kernel<<<grid, 256, 0, stream>>>(pred, label, seq_lens, ws,
                                              (float*)d_out);
}

// Round 4
// 113.722 us; speedup vs baseline: 1.3566x; 1.3566x over previous
//
#include <hip/hip_runtime.h>

// RSNA loss: pred/label [128, 8192, 10] fp32, seq_lens [128] i32 -> scalar fp32.
//
// Structure (R1-best, reverted from the fused R3 which hit the device-scope
// fence trap: per-block __threadfence() on a 1024-block grid = L2
// writeback/inv per block on non-coherent XCD L2s -> 65 us kernel, VALUBusy 2%).
//
//   memset: zero row_acc[128][20] (10 KB, ~1 us node).
//   kernel 1: grid (128 rows x 16), 256 thr, 32 waves/CU. chunk <= 512 so each
//     thread loads exactly one 2-record pair (80 B = 5x float4 per tensor),
//     block-reduces 20 partials, one atomicAdd per value into row_acc[b].
//     No fences: atomicAdd is device-scope on its own; kernel boundary is the
//     visibility barrier.
//   kernel 2: 1 block, 128 thr, reads only row_acc (10 KB), applies the
//     nonlinear exam-BCE / image weighting, reduces, writes out[0].
//
// Only l < seq_lens[b] is ever read -> ~half of the 84 MB input traffic
// (and the harness's input-restore copies leave inputs L3-resident anyway).

#define L_DIM 8192
#define B_DIM 128
#define C_DIM 10
#define SPLIT 16

#define IMAGE_WEIGHT 0.0736196319f

__device__ __constant__ float EXAM_W[9] = {
    0.0736196319f, 0.09202453988f, 0.1042944785f, 0.1042944785f,
    0.1877300613f, 0.06257668712f, 0.06257668712f, 0.2346625767f,
    0.0782208589f};

__device__ __forceinline__ float bce0(float p, float y) {
  return -(y * __logf(p) + (1.0f - y) * __logf(1.0f - p));
}

__global__ __launch_bounds__(256) void rsna_partial_kernel(
    const float* __restrict__ pred, const float* __restrict__ label,
    const int* __restrict__ seq_lens, float* __restrict__ row_acc) {
  const int b = blockIdx.x;  // 0..127
  const int s = blockIdx.y;  // 0..SPLIT-1
  const int len = seq_lens[b];
  // Even chunk so every block's first record index is even (80-byte pair,
  // 16B-aligned). chunk <= ceil(8192/32)*2 = 512 -> exactly one pair/thread.
  const int chunk = ((len + 2 * SPLIT - 1) / (2 * SPLIT)) * 2;
  const int start = s * chunk;
  const int end = min(start + chunk, len);

  float sp[9], sl[9];
#pragma unroll
  for (int c = 0; c < 9; ++c) {
    sp[c] = 0.0f;
    sl[c] = 0.0f;
  }
  float sy0 = 0.0f;
  float sbce = 0.0f;

  const int l = start + 2 * (int)threadIdx.x;
  if (l < end) {
    const size_t base = ((size_t)b * L_DIM + (size_t)l) * C_DIM;
    if (l + 1 < end) {
      // Two records = 80 bytes = 5x float4 per tensor.
      const float4* p4 = reinterpret_cast<const float4*>(pred + base);
      const float4* y4 = reinterpret_cast<const float4*>(label + base);
      float p[20], y[20];
#pragma unroll
      for (int i = 0; i < 5; ++i) {
        float4 pv = p4[i];
        float4 yv = y4[i];
        p[4 * i] = pv.x; p[4 * i + 1] = pv.y; p[4 * i + 2] = pv.z; p[4 * i + 3] = pv.w;
        y[4 * i] = yv.x; y[4 * i + 1] = yv.y; y[4 * i + 2] = yv.z; y[4 * i + 3] = yv.w;
      }
#pragma unroll
      for (int c = 0; c < 9; ++c) {
        sp[c] = p[c + 1] + p[c + 11];
        sl[c] = y[c + 1] + y[c + 11];
      }
      sy0 = y[0] + y[10];
      sbce = bce0(p[0], y[0]) + bce0(p[10], y[10]);
    } else {
      // Odd-length tail: single 40-byte record via 5x float2.
      const float2* p2 = reinterpret_cast<const float2*>(pred + base);
      const float2* y2 = reinterpret_cast<const float2*>(label + base);
      float p[10], y[10];
#pragma unroll
      for (int i = 0; i < 5; ++i) {
        float2 pv = p2[i];
        float2 yv = y2[i];
        p[2 * i] = pv.x; p[2 * i + 1] = pv.y;
        y[2 * i] = yv.x; y[2 * i + 1] = yv.y;
      }
#pragma unroll
      for (int c = 0; c < 9; ++c) {
        sp[c] = p[c + 1];
        sl[c] = y[c + 1];
      }
      sy0 = y[0];
      sbce = bce0(p[0], y[0]);
    }
  }

  float vals[20];
#pragma unroll
  for (int c = 0; c < 9; ++c) {
    vals[c] = sp[c];
    vals[9 + c] = sl[c];
  }
  vals[18] = sy0;
  vals[19] = sbce;

#pragma unroll
  for (int i = 0; i < 20; ++i) {
    float v = vals[i];
#pragma unroll
    for (int off = 32; off > 0; off >>= 1) v += __shfl_down(v, off, 64);
    vals[i] = v;
  }

  __shared__ float lds[4][20];
  const int wave = threadIdx.x >> 6;
  const int lane = threadIdx.x & 63;
  if (lane == 0) {
#pragma unroll
    for (int i = 0; i < 20; ++i) lds[wave][i] = vals[i];
  }
  __syncthreads();
  if (threadIdx.x < 20) {
    const float v = lds[0][threadIdx.x] + lds[1][threadIdx.x] +
                    lds[2][threadIdx.x] + lds[3][threadIdx.x];
    atomicAdd(&row_acc[b * 20 + (int)threadIdx.x], v);
  }
}

__global__ __launch_bounds__(128) void rsna_final_kernel(
    const float* __restrict__ row_acc, const int* __restrict__ seq_lens,
    float* __restrict__ out) {
  const int b = threadIdx.x;  // 0..127
  const float* r = row_acc + b * 20;
  const float len = (float)seq_lens[b];
  const float inv_len = 1.0f / len;

  float exam = 0.0f;
#pragma unroll
  for (int c = 0; c < 9; ++c) {
    const float pm = r[c] * inv_len;
    const float ym = r[9 + c] * inv_len;
    exam += EXAM_W[c] * (-(ym * __logf(pm) + (1.0f - ym) * __logf(1.0f - pm)));
  }
  const float sy0 = r[18];
  const float sbce = r[19];
  const float img_w = IMAGE_WEIGHT * sy0 * inv_len;  // IMAGE_WEIGHT * mean(y0)
  float numer = exam + sbce * img_w;                 // this row's loss
  float wext = IMAGE_WEIGHT * sy0;                   // img_w * len

#pragma unroll
  for (int off = 32; off > 0; off >>= 1) {
    numer += __shfl_down(numer, off, 64);
    wext += __shfl_down(wext, off, 64);
  }

  __shared__ float lds[4];
  if ((threadIdx.x & 63) == 0) {
    const int wave = threadIdx.x >> 6;
    lds[wave * 2] = numer;
    lds[wave * 2 + 1] = wext;
  }
  __syncthreads();
  if (threadIdx.x == 0) {
    float wsum = 0.0f;
#pragma unroll
    for (int c = 0; c < 9; ++c) wsum += EXAM_W[c];
    const float n = lds[0] + lds[2];
    const float w = lds[1] + lds[3];
    out[0] = n / ((float)B_DIM * wsum + w);
  }
}

extern "C" void kernel_launch(void* const* d_in, const int* in_sizes, int n_in,
                              void* d_out, int out_size, void* d_ws,
                              size_t ws_size, hipStream_t stream) {
  const float* pred = (const float*)d_in[0];
  const float* label = (const float*)d_in[1];
  const int* seq_lens = (const int*)d_in[2];
  float* row_acc = (float*)d_ws;  // 128*20 floats = 10 KB

  hipMemsetAsync(d_ws, 0, B_DIM * 20 * sizeof(float), stream);
  dim3 grid(B_DIM, SPLIT);
  rsna_partial_kernel<<<grid, 256, 0, stream>>>(pred, label, seq_lens, row_acc);
  rsna_final_kernel<<<1, 128, 0, stream>>>(row_acc, seq_lens, (float*)d_out);
}